// Round 1
// baseline (525.687 us; speedup 1.0000x reference)
//
#include <hip/hip_runtime.h>
#include <hip/hip_bf16.h>

// Problem constants (from reference): B=32, HQ=32, HKV=8, D=128, T=2048
#define NB 32
#define NHQ 32
#define NHKV 8
#define GQ 4          // HQ / HKV
#define DD 128
#define TT 2048
#define NSPLIT 8
#define CHUNK 256     // TT / NSPLIT

__device__ __forceinline__ float warp_max(float v) {
#pragma unroll
    for (int o = 32; o >= 1; o >>= 1) v = fmaxf(v, __shfl_xor(v, o));
    return v;
}
__device__ __forceinline__ float warp_sum(float v) {
#pragma unroll
    for (int o = 32; o >= 1; o >>= 1) v += __shfl_xor(v, o);
    return v;
}

// Pass 1: per (split, kv_head, batch) partial flash-attention over a 256-token chunk.
__global__ __launch_bounds__(256) void attn_part_kernel(
    const float* __restrict__ q,       // [B, HQ*D]
    const float* __restrict__ knew,    // [B, HKV*D]
    const float* __restrict__ vnew,    // [B, HKV*D]
    const float* __restrict__ kbuf,    // [POOL, HKV, D]
    const float* __restrict__ vbuf,    // [POOL, HKV, D]
    const int* __restrict__ req_to_token,     // [B, T]
    const int* __restrict__ req_pool_indices, // [B]
    const int* __restrict__ seq_lens,         // [B]
    const int* __restrict__ out_cache_loc,    // [B]
    float* __restrict__ part_o,   // [B][HKV][GQ][NSPLIT][D]
    float* __restrict__ part_ml)  // [B][HKV][GQ][NSPLIT][2]
{
    const int tid   = threadIdx.x;
    const int split = blockIdx.x;
    const int kv    = blockIdx.y;
    const int b     = blockIdx.z;

    const int sl = seq_lens[b];
    const int t0 = split * CHUNK;
    const int nt = min(sl - t0, CHUNK);   // tokens in this chunk (may be <=0)

    float* po  = part_o  + (((size_t)b * NHKV + kv) * GQ) * NSPLIT * DD;
    float* pml = part_ml + (((size_t)b * NHKV + kv) * GQ) * NSPLIT * 2;

    if (nt <= 0) {
        // empty chunk: write neutral partials (combine pass reads every split)
        for (int i = tid; i < GQ * DD; i += 256) {
            const int g = i >> 7, d = i & 127;
            po[(g * NSPLIT + split) * DD + d] = 0.f;
        }
        if (tid < GQ) {
            pml[(tid * NSPLIT + split) * 2 + 0] = -1e30f;
            pml[(tid * NSPLIT + split) * 2 + 1] = 0.f;
        }
        return;
    }

    __shared__ __align__(16) float qs[GQ][DD];       // 2 KB
    __shared__ float ps[GQ][CHUNK];                  // 4 KB
    __shared__ int   slot_s[CHUNK];                  // 1 KB
    __shared__ float redm[GQ][4];
    __shared__ float msh[GQ], lsh[GQ];
    __shared__ __align__(16) float opart[4][GQ][DD]; // 8 KB

    // load q for the 4 grouped heads: q.reshape(B, HKV, GQ, D)
    const float* qb = q + ((size_t)b * NHQ + kv * GQ) * DD;
    for (int i = tid; i < GQ * DD; i += 256) qs[i >> 7][i & 127] = qb[i];

    const int req = req_pool_indices[b];
    const int ocl = out_cache_loc[b];
    __syncthreads();

    // ---- score phase: one token per thread ----
    constexpr float SCALING   = 0.08838834764831845f;
    constexpr float LOGIT_CAP = 30.0f;
    float sc0, sc1, sc2, sc3;
    {
        const int t = tid;
        if (t < nt) {
            const int slot = req_to_token[(size_t)req * TT + t0 + t];
            slot_s[t] = slot;
            const float* krow = (slot == ocl)
                ? (knew + ((size_t)b * NHKV + kv) * DD)
                : (kbuf + ((size_t)slot * NHKV + kv) * DD);
            float d0 = 0.f, d1 = 0.f, d2 = 0.f, d3 = 0.f;
#pragma unroll 8
            for (int d = 0; d < DD; d += 4) {
                const float4 kk = *(const float4*)(krow + d);
                const float4 q0 = *(const float4*)(&qs[0][d]);
                const float4 q1 = *(const float4*)(&qs[1][d]);
                const float4 q2 = *(const float4*)(&qs[2][d]);
                const float4 q3 = *(const float4*)(&qs[3][d]);
                d0 += kk.x * q0.x + kk.y * q0.y + kk.z * q0.z + kk.w * q0.w;
                d1 += kk.x * q1.x + kk.y * q1.y + kk.z * q1.z + kk.w * q1.w;
                d2 += kk.x * q2.x + kk.y * q2.y + kk.z * q2.z + kk.w * q2.w;
                d3 += kk.x * q3.x + kk.y * q3.y + kk.z * q3.z + kk.w * q3.w;
            }
            const float c = SCALING / LOGIT_CAP;
            sc0 = LOGIT_CAP * tanhf(d0 * c);
            sc1 = LOGIT_CAP * tanhf(d1 * c);
            sc2 = LOGIT_CAP * tanhf(d2 * c);
            sc3 = LOGIT_CAP * tanhf(d3 * c);
        } else {
            sc0 = sc1 = sc2 = sc3 = -1e30f;
        }
    }

    float scs[GQ] = {sc0, sc1, sc2, sc3};
    // block max per head
#pragma unroll
    for (int g = 0; g < GQ; g++) {
        const float m = warp_max(scs[g]);
        if ((tid & 63) == 0) redm[g][tid >> 6] = m;
    }
    __syncthreads();
    if (tid < GQ) {
        const float* r = redm[tid];
        msh[tid] = fmaxf(fmaxf(r[0], r[1]), fmaxf(r[2], r[3]));
    }
    __syncthreads();
    // exp + block sum per head
#pragma unroll
    for (int g = 0; g < GQ; g++) {
        const float p = (tid < nt) ? __expf(scs[g] - msh[g]) : 0.f;
        ps[g][tid] = p;
        const float l = warp_sum(p);
        if ((tid & 63) == 0) redm[g][tid >> 6] = l;
    }
    __syncthreads();
    if (tid < GQ) {
        const float* r = redm[tid];
        lsh[tid] = r[0] + r[1] + r[2] + r[3];
    }
    __syncthreads();

    // ---- PV phase: wave w handles tokens t ≡ w (mod 4); lane owns 2 dims ----
    {
        const int w = tid >> 6, lane = tid & 63;
        const int d0 = lane << 1;
        float a0x = 0.f, a0y = 0.f, a1x = 0.f, a1y = 0.f;
        float a2x = 0.f, a2y = 0.f, a3x = 0.f, a3y = 0.f;
        const float* vnewrow = vnew + ((size_t)b * NHKV + kv) * DD;
        for (int t = w; t < nt; t += 4) {
            const int slot = slot_s[t];
            const float* vrow = (slot == ocl)
                ? vnewrow
                : (vbuf + ((size_t)slot * NHKV + kv) * DD);
            const float2 vv = *(const float2*)(vrow + d0);
            const float p0 = ps[0][t], p1 = ps[1][t], p2 = ps[2][t], p3 = ps[3][t];
            a0x += p0 * vv.x; a0y += p0 * vv.y;
            a1x += p1 * vv.x; a1y += p1 * vv.y;
            a2x += p2 * vv.x; a2y += p2 * vv.y;
            a3x += p3 * vv.x; a3y += p3 * vv.y;
        }
        *(float2*)&opart[w][0][d0] = make_float2(a0x, a0y);
        *(float2*)&opart[w][1][d0] = make_float2(a1x, a1y);
        *(float2*)&opart[w][2][d0] = make_float2(a2x, a2y);
        *(float2*)&opart[w][3][d0] = make_float2(a3x, a3y);
    }
    __syncthreads();
    // cross-wave reduce + store partials
    for (int i = tid; i < GQ * DD; i += 256) {
        const int g = i >> 7, d = i & 127;
        const float s = opart[0][g][d] + opart[1][g][d] + opart[2][g][d] + opart[3][g][d];
        po[(g * NSPLIT + split) * DD + d] = s;
    }
    if (tid < GQ) {
        pml[(tid * NSPLIT + split) * 2 + 0] = msh[tid];
        pml[(tid * NSPLIT + split) * 2 + 1] = lsh[tid];
    }
}

// Pass 2: combine NSPLIT partials per (b, hq) head.
__global__ __launch_bounds__(128) void attn_combine_kernel(
    const float* __restrict__ part_o,   // [B][HKV][GQ][NSPLIT][D]
    const float* __restrict__ part_ml,  // [B][HKV][GQ][NSPLIT][2]
    float* __restrict__ out)            // [B, HQ*D]
{
    const int h  = blockIdx.x;        // 0 .. B*HQ-1
    const int d  = threadIdx.x;       // 0 .. 127
    const int b  = h >> 5;            // / HQ
    const int hq = h & 31;            // kv*GQ + g

    const float* ml = part_ml + ((size_t)b * NHKV * GQ + hq) * NSPLIT * 2;
    float M = -1e30f;
#pragma unroll
    for (int s = 0; s < NSPLIT; s++) M = fmaxf(M, ml[s * 2]);
    float L = 0.f;
#pragma unroll
    for (int s = 0; s < NSPLIT; s++) L += ml[s * 2 + 1] * __expf(ml[s * 2] - M);

    const float* po = part_o + ((size_t)b * NHKV * GQ + hq) * NSPLIT * DD;
    float acc = 0.f;
#pragma unroll
    for (int s = 0; s < NSPLIT; s++) acc += po[s * DD + d] * __expf(ml[s * 2] - M);

    out[((size_t)b * NHQ + hq) * DD + d] = acc / L;
}

extern "C" void kernel_launch(void* const* d_in, const int* in_sizes, int n_in,
                              void* d_out, int out_size, void* d_ws, size_t ws_size,
                              hipStream_t stream) {
    (void)in_sizes; (void)n_in; (void)out_size; (void)ws_size;
    const float* q    = (const float*)d_in[0];
    const float* k    = (const float*)d_in[1];
    const float* v    = (const float*)d_in[2];
    const float* kbuf = (const float*)d_in[3];
    const float* vbuf = (const float*)d_in[4];
    const int* req_to_token     = (const int*)d_in[5];
    const int* req_pool_indices = (const int*)d_in[6];
    const int* seq_lens         = (const int*)d_in[7];
    const int* out_cache_loc    = (const int*)d_in[8];
    float* out = (float*)d_out;

    float* part_o  = (float*)d_ws;                                  // 4 MB
    float* part_ml = part_o + (size_t)NB * NHKV * GQ * NSPLIT * DD; // 64 KB

    dim3 g1(NSPLIT, NHKV, NB), b1(256);
    attn_part_kernel<<<g1, b1, 0, stream>>>(q, k, v, kbuf, vbuf,
        req_to_token, req_pool_indices, seq_lens, out_cache_loc,
        part_o, part_ml);

    dim3 g2(NB * NHQ), b2(128);
    attn_combine_kernel<<<g2, b2, 0, stream>>>(part_o, part_ml, out);
}